// Round 17
// baseline (754.625 us; speedup 1.0000x reference)
//
#include <hip/hip_runtime.h>
#include <cstdint>

#define NPRED 25200      // total predictions (8400 positions * 3 anchors)
#define NCLS  80
#define CAP   512        // max boxes per class (mean ~315, sigma ~18)
#define MW    8          // u64 mask words per row (512/64)
#define NCHUNK 132       // 64-position chunks: 100 (s0) + 25 (s1) + 7 (s2 tail)
#define REP   16         // DIAGNOSTIC replication (idempotent phases); rev to 1 next round

__device__ __forceinline__ float sigmoidf_(float x) { return 1.0f / (1.0f + expf(-x)); }

// Block = (64-position chunk, anchor), 64 threads. REGISTER-RESIDENT class
// logits. Measured ~4.5us (R12 attribution). Op order exact.
__global__ __launch_bounds__(64, 2) void decode_kernel(
    const float* __restrict__ ps, const float* __restrict__ pm, const float* __restrict__ pl,
    float* __restrict__ out,
    float4* __restrict__ g_boxin, uint64_t* __restrict__ g_key)
{
    int chunk = blockIdx.x;
    int a     = blockIdx.y;
    int t     = threadIdx.x;

    const float* p; int HW, W, base, si; float stride; int w0;
    if (chunk < 100)      { p = ps; HW = 6400; W = 80; stride = 8.f;  base = 0;    si = 0; w0 = chunk * 64; }
    else if (chunk < 125) { p = pm; HW = 1600; W = 40; stride = 16.f; base = 6400; si = 1; w0 = (chunk - 100) * 64; }
    else                  { p = pl; HW = 400;  W = 20; stride = 32.f; base = 8000; si = 2; w0 = (chunk - 125) * 64; }

    int local = w0 + t;
    bool valid = local < HW;
    int lclamp = valid ? local : (HW - 1);

    const float* cbase = p + (size_t)(3 + a * NCLS) * HW + lclamp;
    float v[NCLS];
#pragma unroll
    for (int c = 0; c < NCLS; c++) v[c] = cbase[(size_t)c * HW];

    float objl = p[(size_t)a * HW + lclamp];
    const float* rb = p + (size_t)(3 + 3 * NCLS + a * 4) * HW + lclamp;
    float tx = rb[0], ty = rb[(size_t)HW], tw = rb[(size_t)2 * HW], th = rb[(size_t)3 * HW];

    float m = -INFINITY;
#pragma unroll
    for (int c = 0; c < NCLS; c++) m = fmaxf(m, v[c]);
    float s = 0.f; float beste = -1.f; int bi = 0;
#pragma unroll
    for (int c = 0; c < NCLS; c++) {
        float e = expf(v[c] - m);
        s += e;
        if (e > beste) { beste = e; bi = c; }
    }
    float obj = sigmoidf_(objl);
    float best = beste / s * obj;             // == ref's (e/s)*obj at argmax

    if (!valid) return;

    const float AW[9] = {10.f,16.f,33.f, 30.f,62.f,59.f, 116.f,156.f,373.f};
    const float AH[9] = {13.f,30.f,23.f, 61.f,45.f,119.f, 90.f,198.f,326.f};
    float aw = AW[si*3 + a], ah = AH[si*3 + a];

    int y = local / W;
    int x = local - y * W;
    float cx = (sigmoidf_(tx) + (float)x) * stride;
    float cy = (sigmoidf_(ty) + (float)y) * stride;
    float bw = expf(tw) * aw;
    float bh = expf(th) * ah;
    float x1 = fminf(fmaxf((cx - bw / 2.f) / 640.f, 0.f), 1.f);
    float y1 = fminf(fmaxf((cy - bh / 2.f) / 640.f, 0.f), 1.f);
    float x2 = fminf(fmaxf((cx + bw / 2.f) / 640.f, 0.f), 1.f);
    float y2 = fminf(fmaxf((cy + bh / 2.f) / 640.f, 0.f), 1.f);

    int g = (base + local) * 3 + a;           // reference global ordering
    float clsf = (float)bi;
    float* o = out + (size_t)g * 7;
    o[0] = x1; o[1] = y1; o[2] = x2; o[3] = y2;
    o[4] = best; o[5] = clsf; o[6] = 0.f;

    if (best >= 0.001f) {
        float off2 = clsf * 2.0f;             // ref IoU uses class-offset boxes
        g_boxin[g] = make_float4(x1 + off2, y1 + off2, x2 + off2, y2 + off2);
        unsigned u = __float_as_uint(best);
        u = (u & 0x80000000u) ? ~u : (u | 0x80000000u);
        g_key[g] = ((uint64_t)bi << 47) | ((uint64_t)(~u) << 15) | (uint64_t)g;
    } else {
        g_key[g] = (uint64_t)127 << 47;       // sentinel class: never matched
    }
}

// K2: per-class bucket + rank-by-count sort -> global sorted boxes/ids.
// Body idempotent; REPx16 with opaque zr defeats LICM/store-sinking so the
// dispatch duration = 16x the real phase cost (visible above top-5 cutoff).
__global__ __launch_bounds__(1024, 4) void sort_kernel(
    const uint64_t* __restrict__ g_key, const float4* __restrict__ g_boxin,
    float4* __restrict__ g_sbox, int* __restrict__ g_sg, int* __restrict__ g_n)
{
    int c = blockIdx.x;
    int tid = threadIdx.x;
    int wid = tid >> 6, lane = tid & 63;

    __shared__ alignas(16) uint64_t key_s[CAP];
    __shared__ float4 boxu_s[CAP];
    __shared__ int wsum[16];

    for (int rep = 0; rep < REP; rep++) {
        int zr = rep - rep;                   // 0, but opaque to the compiler
        asm volatile("" : "+v"(zr));
        __syncthreads();                      // wsum/key_s reuse guard

        const ulonglong2* kp = (const ulonglong2*)g_key;
        int cnt = 0;
#pragma unroll
        for (int j = 0; j < 13; j++) {
            int idx = j * 1024 + tid + zr;
            if (idx < NPRED / 2) {
                ulonglong2 kv = kp[idx];
                cnt += ((int)(kv.x >> 47) == c) + ((int)(kv.y >> 47) == c);
            }
        }
        int pre = cnt;
#pragma unroll
        for (int d = 1; d < 64; d <<= 1) {
            int vv = __shfl_up(pre, d);
            if (lane >= d) pre += vv;
        }
        if (lane == 63) wsum[wid] = pre;
        __syncthreads();
        int wbase = 0, ntot = 0;
#pragma unroll
        for (int wq = 0; wq < 16; wq++) {
            int t16 = wsum[wq];
            if (wq < wid) wbase += t16;
            ntot += t16;
        }
        int base = wbase + pre - cnt;
        {
            int wr = base;
#pragma unroll
            for (int j = 0; j < 13; j++) {
                int idx = j * 1024 + tid + zr;
                if (idx < NPRED / 2) {
                    ulonglong2 kv = kp[idx];
                    if ((int)(kv.x >> 47) == c && wr < CAP) key_s[wr++] = kv.x;
                    if ((int)(kv.y >> 47) == c && wr < CAP) key_s[wr++] = kv.y;
                }
            }
        }
        __syncthreads();
        int n = ntot; if (n > CAP) n = CAP;
        if (tid == 0) g_n[c] = n;
        if (n == 0) return;                   // uniform every rep
        for (int i = tid; i < n; i += 1024)
            boxu_s[i] = g_boxin[key_s[i] & 0x7FFF];
        __syncthreads();

        for (int i0 = 0; i0 < n; i0 += 256) {
            int item = i0 + (tid >> 2) + zr;
            int sub  = tid & 3;
            bool act = item < n;
            int r = 0;
            uint64_t k = 0;
            if (act) {
                k = key_s[item];
                int nq = (((n + 3) >> 2) + 1) & ~1;    // even, >= ceil(n/4)
                int lo = sub * nq + zr; if (lo > n) lo = n;
                int hi = lo + nq;  if (hi > n) hi = n;
                int jj = lo;
                for (; jj + 8 <= hi; jj += 8) {        // 4x ds_read_b128 in flight
                    ulonglong2 p0 = *(const ulonglong2*)&key_s[jj];
                    ulonglong2 p1 = *(const ulonglong2*)&key_s[jj + 2];
                    ulonglong2 p2 = *(const ulonglong2*)&key_s[jj + 4];
                    ulonglong2 p3 = *(const ulonglong2*)&key_s[jj + 6];
                    r += (p0.x < k) + (p0.y < k) + (p1.x < k) + (p1.y < k)
                       + (p2.x < k) + (p2.y < k) + (p3.x < k) + (p3.y < k);
                }
                for (; jj + 2 <= hi; jj += 2) {
                    ulonglong2 p0 = *(const ulonglong2*)&key_s[jj];
                    r += (p0.x < k) + (p0.y < k);
                }
                if (jj < hi) r += (key_s[jj] < k);
            }
            r += __shfl_xor(r, 1);
            r += __shfl_xor(r, 2);
            if (act && sub == 0) {
                g_sbox[c * CAP + r] = boxu_s[item];
                g_sg[c * CAP + r]   = (int)(k & 0x7FFF);
            }
        }
    }
}

// exact ref IoU expression/order; sets bit JQ of `bits`
#define IOUBIT(BJ, JQ)                                                   \
    {                                                                    \
        float xx1 = fmaxf(b4.x, (BJ).x);                                 \
        float yy1 = fmaxf(b4.y, (BJ).y);                                 \
        float xx2 = fminf(b4.z, (BJ).z);                                 \
        float yy2 = fminf(b4.w, (BJ).w);                                 \
        float ww = fmaxf(1e-28f, xx2 - xx1);                             \
        float hh = fmaxf(1e-28f, yy2 - yy1);                             \
        float inter = ww * hh;                                           \
        float Aj = ((BJ).z - (BJ).x) * ((BJ).w - (BJ).y);                \
        float iou = inter / ((Ai + Aj) - inter);                         \
        if ((j0 + (JQ)) > i && iou > 0.6f) bits |= 1ull << (JQ);         \
    }

// K3: upper-triangle mask build -> global. 80 blocks (16 waves cover T<=36
// tiles). REPx16 diagnostic.
__global__ __launch_bounds__(1024, 4) void build_kernel(
    const int* __restrict__ g_n, const float4* __restrict__ g_sbox,
    uint64_t* __restrict__ g_mask)
{
    int c = blockIdx.x;
    int tid = threadIdx.x, wid = tid >> 6, lane = tid & 63;
    int n = g_n[c]; if (n == 0) return;
    int nw = (n + 63) >> 6;

    __shared__ float4 sbox_s[CAP + 64];
    for (int i = tid; i < n; i += 1024) sbox_s[i] = g_sbox[c * CAP + i];
    for (int i = n + tid; i < n + 64; i += 1024)
        sbox_s[i] = make_float4(3e30f, 3e30f, 3e30f, 3e30f);
    __syncthreads();

    uint64_t* gm = g_mask + (size_t)c * MW * CAP;
    int T = nw * (nw + 1) / 2;
    for (int rep = 0; rep < REP; rep++) {
        int zr = rep - rep;
        asm volatile("" : "+v"(zr));
        for (int t = wid; t < T; t += 16) {
            int w = 0, acc = 0;               // triangular decode (wave-uniform)
            while (t >= acc + w + 1) { acc += w + 1; w++; }
            int ib = t - acc;
            int i  = (ib << 6) + lane + zr;   // <= n+62 (covered by pad)
            float4 b4 = sbox_s[i];
            float Ai = (b4.z - b4.x) * (b4.w - b4.y);
            int j0 = (w << 6) + zr;
            uint64_t bits = 0;
#pragma unroll
            for (int jq0 = 0; jq0 < 64; jq0 += 8) {
                float4 q0 = sbox_s[j0 + jq0 + 0];
                float4 q1 = sbox_s[j0 + jq0 + 1];
                float4 q2 = sbox_s[j0 + jq0 + 2];
                float4 q3 = sbox_s[j0 + jq0 + 3];
                float4 q4 = sbox_s[j0 + jq0 + 4];
                float4 q5 = sbox_s[j0 + jq0 + 5];
                float4 q6 = sbox_s[j0 + jq0 + 6];
                float4 q7 = sbox_s[j0 + jq0 + 7];
                IOUBIT(q0, jq0 + 0); IOUBIT(q1, jq0 + 1);
                IOUBIT(q2, jq0 + 2); IOUBIT(q3, jq0 + 3);
                IOUBIT(q4, jq0 + 4); IOUBIT(q5, jq0 + 5);
                IOUBIT(q6, jq0 + 6); IOUBIT(q7, jq0 + 7);
            }
            if (i < n) gm[w * CAP + i] = bits;
        }
    }
}

// K4: greedy scan (wave0 batch-8 chain + predicated 8-read fold) from L2
// masks. REPx16 diagnostic (removed resets per rep; keep-writes idempotent).
__global__ __launch_bounds__(64) void scan_kernel(
    const int* __restrict__ g_n, const int* __restrict__ g_sg,
    const uint64_t* __restrict__ g_mask, float* __restrict__ out)
{
    int c = blockIdx.x;
    int lane = threadIdx.x;
    int n = g_n[c]; if (n == 0) return;
    int nw = (n + 63) >> 6;
    const uint64_t* gm = g_mask + (size_t)c * MW * CAP;
    const int* sg = g_sg + c * CAP;

    for (int rep = 0; rep < REP; rep++) {
        int zr = rep - rep;
        asm volatile("" : "+v"(zr));
        uint64_t removed = 0;                 // lane L<8 holds word L
        for (int w = 0; w < nw; w++) {
            uint64_t rw = __shfl(removed, w);
            int row = (w << 6) + lane + zr;
            uint64_t diag = (row < n) ? gm[w * CAP + row] : 0ull;
            int rem = n - (w << 6);
            uint64_t valid = (rem >= 64) ? ~0ull : ((1ull << rem) - 1ull);
            uint64_t nulls = __ballot(diag == 0ull);
            uint64_t cand = ~rw & valid;
            uint64_t kw = 0;
            uint64_t it = cand & ~nulls;
            while (it) {                      // batch-8 speculative chain
                uint64_t tmp = it;
                int b0 = __ffsll((unsigned long long)tmp) - 1; tmp &= tmp - 1;
                int b1 = tmp ? __ffsll((unsigned long long)tmp) - 1 : -1; tmp &= tmp - 1;
                int b2 = tmp ? __ffsll((unsigned long long)tmp) - 1 : -1; tmp &= tmp - 1;
                int b3 = tmp ? __ffsll((unsigned long long)tmp) - 1 : -1; tmp &= tmp - 1;
                int b4i = tmp ? __ffsll((unsigned long long)tmp) - 1 : -1; tmp &= tmp - 1;
                int b5 = tmp ? __ffsll((unsigned long long)tmp) - 1 : -1; tmp &= tmp - 1;
                int b6 = tmp ? __ffsll((unsigned long long)tmp) - 1 : -1; tmp &= tmp - 1;
                int b7 = tmp ? __ffsll((unsigned long long)tmp) - 1 : -1;
                uint64_t d0 = __shfl(diag, b0);
                uint64_t d1 = __shfl(diag, b1 < 0 ? 0 : b1);
                uint64_t d2 = __shfl(diag, b2 < 0 ? 0 : b2);
                uint64_t d3 = __shfl(diag, b3 < 0 ? 0 : b3);
                uint64_t d4 = __shfl(diag, b4i < 0 ? 0 : b4i);
                uint64_t d5 = __shfl(diag, b5 < 0 ? 0 : b5);
                uint64_t d6 = __shfl(diag, b6 < 0 ? 0 : b6);
                uint64_t d7 = __shfl(diag, b7 < 0 ? 0 : b7);
                uint64_t rm = 0, proc = 1ull << b0;
                kw |= 1ull << b0; rm |= d0;
                if (b1 >= 0) { proc |= 1ull << b1; if (!((rm >> b1) & 1)) { kw |= 1ull << b1; rm |= d1; } }
                if (b2 >= 0) { proc |= 1ull << b2; if (!((rm >> b2) & 1)) { kw |= 1ull << b2; rm |= d2; } }
                if (b3 >= 0) { proc |= 1ull << b3; if (!((rm >> b3) & 1)) { kw |= 1ull << b3; rm |= d3; } }
                if (b4i >= 0) { proc |= 1ull << b4i; if (!((rm >> b4i) & 1)) { kw |= 1ull << b4i; rm |= d4; } }
                if (b5 >= 0) { proc |= 1ull << b5; if (!((rm >> b5) & 1)) { kw |= 1ull << b5; rm |= d5; } }
                if (b6 >= 0) { proc |= 1ull << b6; if (!((rm >> b6) & 1)) { kw |= 1ull << b6; rm |= d6; } }
                if (b7 >= 0) { proc |= 1ull << b7; if (!((rm >> b7) & 1)) { kw |= 1ull << b7; rm |= d7; } }
                it &= ~rm; cand &= ~rm;
                it &= ~proc;
            }
            kw |= cand & nulls;

            int g  = lane >> 3;
            int wp = lane & 7;
            uint64_t acc = 0;
            if (wp >= w && wp < nw) {         // lower-tri words unwritten
                int rbase = (w << 6) + (g << 3);
#pragma unroll
                for (int bb = 0; bb < 8; bb++) {
                    uint64_t mword = gm[wp * CAP + rbase + bb];
                    if ((kw >> ((g << 3) + bb)) & 1) acc |= mword;
                }
            }
            acc |= __shfl_xor(acc, 8);
            acc |= __shfl_xor(acc, 16);
            acc |= __shfl_xor(acc, 32);
            if (lane < MW) removed |= acc;

            if (row < n && ((kw >> lane) & 1))
                out[(size_t)sg[row] * 7 + 6] = 1.0f;
        }
    }
}

extern "C" void kernel_launch(void* const* d_in, const int* in_sizes, int n_in,
                              void* d_out, int out_size, void* d_ws, size_t ws_size,
                              hipStream_t stream) {
    const float* ps = (const float*)d_in[0];
    const float* pm = (const float*)d_in[1];
    const float* pl = (const float*)d_in[2];
    float* out = (float*)d_out;

    char* ws = (char*)d_ws;
    float4*   g_boxin = (float4*)ws;                       // 403,200 B (dense by g)
    uint64_t* g_key   = (uint64_t*)(ws + 409600);          // 201,600 B (dense by g)
    int*      g_n     = (int*)(ws + 614400);               // 320 B (padded to 4 KB)
    float4*   g_sbox  = (float4*)(ws + 618496);            // 655,360 B
    int*      g_sg    = (int*)(ws + 1273856);              // 163,840 B
    uint64_t* g_mask  = (uint64_t*)(ws + 1437696);         // 2,621,440 B

    // DIAGNOSTIC pipeline: real production structure split per phase; each
    // NMS kernel self-replicates x16 so its dispatch rises above the 41us
    // top-5 cutoff -> per-phase durations finally measurable (divide by 16).
    decode_kernel<<<dim3(NCHUNK, 3), 64, 0, stream>>>(ps, pm, pl, out, g_boxin, g_key);
    sort_kernel<<<NCLS, 1024, 0, stream>>>(g_key, g_boxin, g_sbox, g_sg, g_n);
    build_kernel<<<NCLS, 1024, 0, stream>>>(g_n, g_sbox, g_mask);
    scan_kernel<<<NCLS, 64, 0, stream>>>(g_n, g_sg, g_mask, out);
}

// Round 18
// 160.257 us; speedup vs baseline: 4.7088x; 4.7088x over previous
//
#include <hip/hip_runtime.h>
#include <cstdint>

#define NPRED 25200      // total predictions (8400 positions * 3 anchors)
#define NCLS  80
#define CAP   512        // max boxes per class (mean ~315, sigma ~18)
#define MW    8          // u64 mask words per row (512/64)
#define NCHUNK 132       // 64-position chunks: 100 (s0) + 25 (s1) + 7 (s2 tail)

__device__ __forceinline__ float sigmoidf_(float x) { return 1.0f / (1.0f + expf(-x)); }

// Block = (64-position chunk, anchor), 64 threads. REGISTER-RESIDENT class
// logits. Measured ~4.5us (R12 attribution). Op order exact.
__global__ __launch_bounds__(64, 2) void decode_kernel(
    const float* __restrict__ ps, const float* __restrict__ pm, const float* __restrict__ pl,
    float* __restrict__ out,
    float4* __restrict__ g_boxin, uint64_t* __restrict__ g_key)
{
    int chunk = blockIdx.x;
    int a     = blockIdx.y;
    int t     = threadIdx.x;

    const float* p; int HW, W, base, si; float stride; int w0;
    if (chunk < 100)      { p = ps; HW = 6400; W = 80; stride = 8.f;  base = 0;    si = 0; w0 = chunk * 64; }
    else if (chunk < 125) { p = pm; HW = 1600; W = 40; stride = 16.f; base = 6400; si = 1; w0 = (chunk - 100) * 64; }
    else                  { p = pl; HW = 400;  W = 20; stride = 32.f; base = 8000; si = 2; w0 = (chunk - 125) * 64; }

    int local = w0 + t;
    bool valid = local < HW;
    int lclamp = valid ? local : (HW - 1);

    const float* cbase = p + (size_t)(3 + a * NCLS) * HW + lclamp;
    float v[NCLS];
#pragma unroll
    for (int c = 0; c < NCLS; c++) v[c] = cbase[(size_t)c * HW];

    float objl = p[(size_t)a * HW + lclamp];
    const float* rb = p + (size_t)(3 + 3 * NCLS + a * 4) * HW + lclamp;
    float tx = rb[0], ty = rb[(size_t)HW], tw = rb[(size_t)2 * HW], th = rb[(size_t)3 * HW];

    float m = -INFINITY;
#pragma unroll
    for (int c = 0; c < NCLS; c++) m = fmaxf(m, v[c]);
    float s = 0.f; float beste = -1.f; int bi = 0;
#pragma unroll
    for (int c = 0; c < NCLS; c++) {
        float e = expf(v[c] - m);
        s += e;
        if (e > beste) { beste = e; bi = c; }
    }
    float obj = sigmoidf_(objl);
    float best = beste / s * obj;             // == ref's (e/s)*obj at argmax

    if (!valid) return;

    const float AW[9] = {10.f,16.f,33.f, 30.f,62.f,59.f, 116.f,156.f,373.f};
    const float AH[9] = {13.f,30.f,23.f, 61.f,45.f,119.f, 90.f,198.f,326.f};
    float aw = AW[si*3 + a], ah = AH[si*3 + a];

    int y = local / W;
    int x = local - y * W;
    float cx = (sigmoidf_(tx) + (float)x) * stride;
    float cy = (sigmoidf_(ty) + (float)y) * stride;
    float bw = expf(tw) * aw;
    float bh = expf(th) * ah;
    float x1 = fminf(fmaxf((cx - bw / 2.f) / 640.f, 0.f), 1.f);
    float y1 = fminf(fmaxf((cy - bh / 2.f) / 640.f, 0.f), 1.f);
    float x2 = fminf(fmaxf((cx + bw / 2.f) / 640.f, 0.f), 1.f);
    float y2 = fminf(fmaxf((cy + bh / 2.f) / 640.f, 0.f), 1.f);

    int g = (base + local) * 3 + a;           // reference global ordering
    float clsf = (float)bi;
    float* o = out + (size_t)g * 7;
    o[0] = x1; o[1] = y1; o[2] = x2; o[3] = y2;
    o[4] = best; o[5] = clsf; o[6] = 0.f;

    if (best >= 0.001f) {
        float off2 = clsf * 2.0f;             // ref IoU uses class-offset boxes
        g_boxin[g] = make_float4(x1 + off2, y1 + off2, x2 + off2, y2 + off2);
        unsigned u = __float_as_uint(best);
        u = (u & 0x80000000u) ? ~u : (u | 0x80000000u);
        g_key[g] = ((uint64_t)bi << 47) | ((uint64_t)(~u) << 15) | (uint64_t)g;
    } else {
        g_key[g] = (uint64_t)127 << 47;       // sentinel class: never matched
    }
}

// K2: grid (class, half) = 160 blocks, 1024 threads. Both half-blocks run
// the deterministic p0 bucket (identical key_s), then each ranks/scatters
// ONE HALF of the items (disjoint writes; ranks computed over all n keys).
__global__ __launch_bounds__(1024, 4) void sort_kernel(
    const uint64_t* __restrict__ g_key, const float4* __restrict__ g_boxin,
    float4* __restrict__ g_sbox, int* __restrict__ g_sg, int* __restrict__ g_n)
{
    int c = blockIdx.x;
    int hid = blockIdx.y;                     // 0 or 1
    int tid = threadIdx.x;
    int wid = tid >> 6, lane = tid & 63;

    __shared__ alignas(16) uint64_t key_s[CAP];
    __shared__ float4 boxu_s[CAP];
    __shared__ int wsum[16];

    // p0 pass 1: count (13 independent ulonglong2 loads)
    const ulonglong2* kp = (const ulonglong2*)g_key;
    int cnt = 0;
#pragma unroll
    for (int j = 0; j < 13; j++) {
        int idx = j * 1024 + tid;
        if (idx < NPRED / 2) {
            ulonglong2 kv = kp[idx];
            cnt += ((int)(kv.x >> 47) == c) + ((int)(kv.y >> 47) == c);
        }
    }
    int pre = cnt;                            // wave-inclusive shfl prefix
#pragma unroll
    for (int d = 1; d < 64; d <<= 1) {
        int vv = __shfl_up(pre, d);
        if (lane >= d) pre += vv;
    }
    if (lane == 63) wsum[wid] = pre;
    __syncthreads();
    int wbase = 0, ntot = 0;
#pragma unroll
    for (int wq = 0; wq < 16; wq++) {
        int t16 = wsum[wq];
        if (wq < wid) wbase += t16;
        ntot += t16;
    }
    int base = wbase + pre - cnt;

    // p0 pass 2: re-read (L2-hot) and write at computed offsets
    {
        int wr = base;
#pragma unroll
        for (int j = 0; j < 13; j++) {
            int idx = j * 1024 + tid;
            if (idx < NPRED / 2) {
                ulonglong2 kv = kp[idx];
                if ((int)(kv.x >> 47) == c && wr < CAP) key_s[wr++] = kv.x;
                if ((int)(kv.y >> 47) == c && wr < CAP) key_s[wr++] = kv.y;
            }
        }
    }
    __syncthreads();
    int n = ntot; if (n > CAP) n = CAP;
    if (tid == 0 && hid == 0) g_n[c] = n;
    if (n == 0) return;                       // uniform

    for (int i = tid; i < n; i += 1024)
        boxu_s[i] = g_boxin[key_s[i] & 0x7FFF];
    __syncthreads();

    // rank-by-count over this block's half (ranks vs ALL n keys; keys
    // unique -> total order; ascending key == (score desc, g asc))
    int h0 = (n + 1) >> 1;
    int lo_i = hid ? h0 : 0;
    int hi_i = hid ? n : h0;
    for (int i0 = lo_i; i0 < hi_i; i0 += 256) {
        int item = i0 + (tid >> 2);
        int sub  = tid & 3;
        bool act = item < hi_i;
        int r = 0;
        uint64_t k = 0;
        if (act) {
            k = key_s[item];
            int nq = (((n + 3) >> 2) + 1) & ~1;    // even, >= ceil(n/4)
            int lo = sub * nq; if (lo > n) lo = n;
            int hi = lo + nq;  if (hi > n) hi = n;
            int jj = lo;
            for (; jj + 8 <= hi; jj += 8) {        // 4x ds_read_b128 in flight
                ulonglong2 p0 = *(const ulonglong2*)&key_s[jj];
                ulonglong2 p1 = *(const ulonglong2*)&key_s[jj + 2];
                ulonglong2 p2 = *(const ulonglong2*)&key_s[jj + 4];
                ulonglong2 p3 = *(const ulonglong2*)&key_s[jj + 6];
                r += (p0.x < k) + (p0.y < k) + (p1.x < k) + (p1.y < k)
                   + (p2.x < k) + (p2.y < k) + (p3.x < k) + (p3.y < k);
            }
            for (; jj + 2 <= hi; jj += 2) {
                ulonglong2 p0 = *(const ulonglong2*)&key_s[jj];
                r += (p0.x < k) + (p0.y < k);
            }
            if (jj < hi) r += (key_s[jj] < k);
        }
        r += __shfl_xor(r, 1);                // quad reduce (4 lanes/item)
        r += __shfl_xor(r, 2);
        if (act && sub == 0) {
            g_sbox[c * CAP + r] = boxu_s[item];
            g_sg[c * CAP + r]   = (int)(k & 0x7FFF);
        }
    }
}

// exact ref IoU expression/order; sets bit JQ of `bits`
#define IOUBIT(BJ, JQ)                                                   \
    {                                                                    \
        float xx1 = fmaxf(b4.x, (BJ).x);                                 \
        float yy1 = fmaxf(b4.y, (BJ).y);                                 \
        float xx2 = fminf(b4.z, (BJ).z);                                 \
        float yy2 = fminf(b4.w, (BJ).w);                                 \
        float ww = fmaxf(1e-28f, xx2 - xx1);                             \
        float hh = fmaxf(1e-28f, yy2 - yy1);                             \
        float inter = ww * hh;                                           \
        float Aj = ((BJ).z - (BJ).x) * ((BJ).w - (BJ).y);                \
        float iou = inter / ((Ai + Aj) - inter);                         \
        if ((j0 + (JQ)) > i && iou > 0.6f) bits |= 1ull << (JQ);         \
    }

// K3: grid (class, word) = 640 blocks, 512 threads. R17 diagnostic: build
// is the dominant phase (19.4us/rep) and VALU-THROUGHPUT-bound on 80 CUs
// (VALUBusy ~80% of active). 640 blocks spreads the IoU math over all 256
// CUs at 2.5 blocks/CU. Block (c,w) writes word w for rows [0,min(n,(w+1)
// *64)) -- exactly the set the scan reads (diag: block-w rows; fold: wp>=w).
__global__ __launch_bounds__(512, 4) void build_kernel(
    const int* __restrict__ g_n, const float4* __restrict__ g_sbox,
    uint64_t* __restrict__ g_mask)
{
    int c = blockIdx.x;
    int w = blockIdx.y;
    int tid = threadIdx.x;
    int n = g_n[c]; if (n == 0) return;
    int nw = (n + 63) >> 6;
    if (w >= nw) return;

    __shared__ float4 sbox_s[CAP + 64];
    for (int i = tid; i < n; i += 512) sbox_s[i] = g_sbox[c * CAP + i];
    for (int i = n + tid; i < n + 64; i += 512)
        sbox_s[i] = make_float4(3e30f, 3e30f, 3e30f, 3e30f);   // sentinel
    __syncthreads();

    int j0 = w << 6;
    int rmax = j0 + 64; if (rmax > n) rmax = n;   // rows needing word w
    uint64_t* gm = g_mask + (size_t)c * MW * CAP + (size_t)w * CAP;
    for (int i = tid; i < rmax; i += 512) {
        float4 b4 = sbox_s[i];
        float Ai = (b4.z - b4.x) * (b4.w - b4.y);
        uint64_t bits = 0;
#pragma unroll
        for (int jq0 = 0; jq0 < 64; jq0 += 8) {   // 8 broadcast b128 reads
            float4 q0 = sbox_s[j0 + jq0 + 0];
            float4 q1 = sbox_s[j0 + jq0 + 1];
            float4 q2 = sbox_s[j0 + jq0 + 2];
            float4 q3 = sbox_s[j0 + jq0 + 3];
            float4 q4 = sbox_s[j0 + jq0 + 4];
            float4 q5 = sbox_s[j0 + jq0 + 5];
            float4 q6 = sbox_s[j0 + jq0 + 6];
            float4 q7 = sbox_s[j0 + jq0 + 7];
            IOUBIT(q0, jq0 + 0); IOUBIT(q1, jq0 + 1);
            IOUBIT(q2, jq0 + 2); IOUBIT(q3, jq0 + 3);
            IOUBIT(q4, jq0 + 4); IOUBIT(q5, jq0 + 5);
            IOUBIT(q6, jq0 + 6); IOUBIT(q7, jq0 + 7);
        }
        gm[i] = bits;
    }
}

// K4: greedy scan (wave0 batch-8 speculative chain + predicated 8-read
// fold), 80 blocks x 64 threads, masks from L2. Kept-set == ref greedy.
__global__ __launch_bounds__(64) void scan_kernel(
    const int* __restrict__ g_n, const int* __restrict__ g_sg,
    const uint64_t* __restrict__ g_mask, float* __restrict__ out)
{
    int c = blockIdx.x;
    int lane = threadIdx.x;
    int n = g_n[c]; if (n == 0) return;
    int nw = (n + 63) >> 6;
    const uint64_t* gm = g_mask + (size_t)c * MW * CAP;
    const int* sg = g_sg + c * CAP;

    uint64_t removed = 0;                     // lane L<8 holds word L
    for (int w = 0; w < nw; w++) {
        uint64_t rw = __shfl(removed, w);
        int row = (w << 6) + lane;
        uint64_t diag = (row < n) ? gm[w * CAP + row] : 0ull;
        int rem = n - (w << 6);
        uint64_t valid = (rem >= 64) ? ~0ull : ((1ull << rem) - 1ull);
        uint64_t nulls = __ballot(diag == 0ull);
        uint64_t cand = ~rw & valid;
        uint64_t kw = 0;
        uint64_t it = cand & ~nulls;
        while (it) {                          // batch-8 speculative chain
            uint64_t tmp = it;
            int b0 = __ffsll((unsigned long long)tmp) - 1; tmp &= tmp - 1;
            int b1 = tmp ? __ffsll((unsigned long long)tmp) - 1 : -1; tmp &= tmp - 1;
            int b2 = tmp ? __ffsll((unsigned long long)tmp) - 1 : -1; tmp &= tmp - 1;
            int b3 = tmp ? __ffsll((unsigned long long)tmp) - 1 : -1; tmp &= tmp - 1;
            int b4i = tmp ? __ffsll((unsigned long long)tmp) - 1 : -1; tmp &= tmp - 1;
            int b5 = tmp ? __ffsll((unsigned long long)tmp) - 1 : -1; tmp &= tmp - 1;
            int b6 = tmp ? __ffsll((unsigned long long)tmp) - 1 : -1; tmp &= tmp - 1;
            int b7 = tmp ? __ffsll((unsigned long long)tmp) - 1 : -1;
            uint64_t d0 = __shfl(diag, b0);
            uint64_t d1 = __shfl(diag, b1 < 0 ? 0 : b1);
            uint64_t d2 = __shfl(diag, b2 < 0 ? 0 : b2);
            uint64_t d3 = __shfl(diag, b3 < 0 ? 0 : b3);
            uint64_t d4 = __shfl(diag, b4i < 0 ? 0 : b4i);
            uint64_t d5 = __shfl(diag, b5 < 0 ? 0 : b5);
            uint64_t d6 = __shfl(diag, b6 < 0 ? 0 : b6);
            uint64_t d7 = __shfl(diag, b7 < 0 ? 0 : b7);
            uint64_t rm = 0, proc = 1ull << b0;
            kw |= 1ull << b0; rm |= d0;       // lowest candidate always kept
            if (b1 >= 0) { proc |= 1ull << b1; if (!((rm >> b1) & 1)) { kw |= 1ull << b1; rm |= d1; } }
            if (b2 >= 0) { proc |= 1ull << b2; if (!((rm >> b2) & 1)) { kw |= 1ull << b2; rm |= d2; } }
            if (b3 >= 0) { proc |= 1ull << b3; if (!((rm >> b3) & 1)) { kw |= 1ull << b3; rm |= d3; } }
            if (b4i >= 0) { proc |= 1ull << b4i; if (!((rm >> b4i) & 1)) { kw |= 1ull << b4i; rm |= d4; } }
            if (b5 >= 0) { proc |= 1ull << b5; if (!((rm >> b5) & 1)) { kw |= 1ull << b5; rm |= d5; } }
            if (b6 >= 0) { proc |= 1ull << b6; if (!((rm >> b6) & 1)) { kw |= 1ull << b6; rm |= d6; } }
            if (b7 >= 0) { proc |= 1ull << b7; if (!((rm >> b7) & 1)) { kw |= 1ull << b7; rm |= d7; } }
            it &= ~rm; cand &= ~rm;
            it &= ~proc;
        }
        kw |= cand & nulls;                   // surviving zero-diag rows kept

        // cooperative fold: lane (g=lane>>3, wp=lane&7) ORs kept rows' word
        // wp over bit-range [8g,8g+8); wp >= w only (lower-tri unwritten;
        // rows >= n read garbage but their kw bits are provably 0).
        int g  = lane >> 3;
        int wp = lane & 7;
        uint64_t acc = 0;
        if (wp >= w && wp < nw) {
            int rbase = (w << 6) + (g << 3);
#pragma unroll
            for (int bb = 0; bb < 8; bb++) {
                uint64_t mword = gm[wp * CAP + rbase + bb];
                if ((kw >> ((g << 3) + bb)) & 1) acc |= mword;
            }
        }
        acc |= __shfl_xor(acc, 8);
        acc |= __shfl_xor(acc, 16);
        acc |= __shfl_xor(acc, 32);
        if (lane < MW) removed |= acc;

        if (row < n && ((kw >> lane) & 1))
            out[(size_t)sg[row] * 7 + 6] = 1.0f;
    }
}

extern "C" void kernel_launch(void* const* d_in, const int* in_sizes, int n_in,
                              void* d_out, int out_size, void* d_ws, size_t ws_size,
                              hipStream_t stream) {
    const float* ps = (const float*)d_in[0];
    const float* pm = (const float*)d_in[1];
    const float* pl = (const float*)d_in[2];
    float* out = (float*)d_out;

    char* ws = (char*)d_ws;
    float4*   g_boxin = (float4*)ws;                       // 403,200 B (dense by g)
    uint64_t* g_key   = (uint64_t*)(ws + 409600);          // 201,600 B (dense by g)
    int*      g_n     = (int*)(ws + 614400);               // 320 B (padded to 4 KB)
    float4*   g_sbox  = (float4*)(ws + 618496);            // 655,360 B
    int*      g_sg    = (int*)(ws + 1273856);              // 163,840 B
    uint64_t* g_mask  = (uint64_t*)(ws + 1437696);         // 2,621,440 B

    decode_kernel<<<dim3(NCHUNK, 3), 64, 0, stream>>>(ps, pm, pl, out, g_boxin, g_key);
    sort_kernel<<<dim3(NCLS, 2), 1024, 0, stream>>>(g_key, g_boxin, g_sbox, g_sg, g_n);
    build_kernel<<<dim3(NCLS, MW), 512, 0, stream>>>(g_n, g_sbox, g_mask);
    scan_kernel<<<NCLS, 64, 0, stream>>>(g_n, g_sg, g_mask, out);
}

// Round 19
// 101.046 us; speedup vs baseline: 7.4681x; 1.5860x over previous
//
#include <hip/hip_runtime.h>
#include <cstdint>

#define NPRED 25200      // total predictions (8400 positions * 3 anchors)
#define NCLS  80
#define CAP   512        // max boxes per class (mean ~315, sigma ~18)
#define MW    8          // u64 mask words per row (512/64)
#define MSTRIDE 514      // mask row stride (u64): breaks 32-way fold conflict
#define NCHUNK 132       // 64-position chunks: 100 (s0) + 25 (s1) + 7 (s2 tail)

__device__ __forceinline__ float sigmoidf_(float x) { return 1.0f / (1.0f + expf(-x)); }

// Block = (64-position chunk, anchor), 64 threads. REGISTER-RESIDENT class
// logits (v[80] in VGPRs; (64,2) bounds -> 256 VGPR cap, no spill).
// Measured ~4.5us (R12 4x-replication attribution). Op order exact.
__global__ __launch_bounds__(64, 2) void decode_kernel(
    const float* __restrict__ ps, const float* __restrict__ pm, const float* __restrict__ pl,
    float* __restrict__ out,
    float4* __restrict__ g_boxin, uint64_t* __restrict__ g_key)
{
    int chunk = blockIdx.x;
    int a     = blockIdx.y;
    int t     = threadIdx.x;

    const float* p; int HW, W, base, si; float stride; int w0;
    if (chunk < 100)      { p = ps; HW = 6400; W = 80; stride = 8.f;  base = 0;    si = 0; w0 = chunk * 64; }
    else if (chunk < 125) { p = pm; HW = 1600; W = 40; stride = 16.f; base = 6400; si = 1; w0 = (chunk - 100) * 64; }
    else                  { p = pl; HW = 400;  W = 20; stride = 32.f; base = 8000; si = 2; w0 = (chunk - 125) * 64; }

    int local = w0 + t;
    bool valid = local < HW;
    int lclamp = valid ? local : (HW - 1);

    const float* cbase = p + (size_t)(3 + a * NCLS) * HW + lclamp;
    float v[NCLS];
#pragma unroll
    for (int c = 0; c < NCLS; c++) v[c] = cbase[(size_t)c * HW];

    float objl = p[(size_t)a * HW + lclamp];
    const float* rb = p + (size_t)(3 + 3 * NCLS + a * 4) * HW + lclamp;
    float tx = rb[0], ty = rb[(size_t)HW], tw = rb[(size_t)2 * HW], th = rb[(size_t)3 * HW];

    // pass A: max (ascending, order-exact)
    float m = -INFINITY;
#pragma unroll
    for (int c = 0; c < NCLS; c++) m = fmaxf(m, v[c]);
    // pass B: serial ascending sum + argmax of e (strict >, ascending)
    float s = 0.f; float beste = -1.f; int bi = 0;
#pragma unroll
    for (int c = 0; c < NCLS; c++) {
        float e = expf(v[c] - m);
        s += e;
        if (e > beste) { beste = e; bi = c; }
    }
    float obj = sigmoidf_(objl);
    float best = beste / s * obj;             // == ref's (e/s)*obj at argmax

    if (!valid) return;

    const float AW[9] = {10.f,16.f,33.f, 30.f,62.f,59.f, 116.f,156.f,373.f};
    const float AH[9] = {13.f,30.f,23.f, 61.f,45.f,119.f, 90.f,198.f,326.f};
    float aw = AW[si*3 + a], ah = AH[si*3 + a];

    int y = local / W;
    int x = local - y * W;
    float cx = (sigmoidf_(tx) + (float)x) * stride;
    float cy = (sigmoidf_(ty) + (float)y) * stride;
    float bw = expf(tw) * aw;
    float bh = expf(th) * ah;
    float x1 = fminf(fmaxf((cx - bw / 2.f) / 640.f, 0.f), 1.f);
    float y1 = fminf(fmaxf((cy - bh / 2.f) / 640.f, 0.f), 1.f);
    float x2 = fminf(fmaxf((cx + bw / 2.f) / 640.f, 0.f), 1.f);
    float y2 = fminf(fmaxf((cy + bh / 2.f) / 640.f, 0.f), 1.f);

    int g = (base + local) * 3 + a;           // reference global ordering
    float clsf = (float)bi;
    float* o = out + (size_t)g * 7;
    o[0] = x1; o[1] = y1; o[2] = x2; o[3] = y2;
    o[4] = best; o[5] = clsf; o[6] = 0.f;

    if (best >= 0.001f) {
        float off2 = clsf * 2.0f;             // ref IoU uses class-offset boxes
        g_boxin[g] = make_float4(x1 + off2, y1 + off2, x2 + off2, y2 + off2);
        unsigned u = __float_as_uint(best);
        u = (u & 0x80000000u) ? ~u : (u | 0x80000000u);
        g_key[g] = ((uint64_t)bi << 47) | ((uint64_t)(~u) << 15) | (uint64_t)g;
    } else {
        g_key[g] = (uint64_t)127 << 47;       // sentinel class: never matched
    }
}

// exact ref IoU expression/order; sets bit JQ of `bits`
#define IOUBIT(BJ, JQ)                                                   \
    {                                                                    \
        float xx1 = fmaxf(b4.x, (BJ).x);                                 \
        float yy1 = fmaxf(b4.y, (BJ).y);                                 \
        float xx2 = fminf(b4.z, (BJ).z);                                 \
        float yy2 = fminf(b4.w, (BJ).w);                                 \
        float ww = fmaxf(1e-28f, xx2 - xx1);                             \
        float hh = fmaxf(1e-28f, yy2 - yy1);                             \
        float inter = ww * hh;                                           \
        float Aj = ((BJ).z - (BJ).x) * ((BJ).w - (BJ).y);                \
        float iou = inter / ((Ai + Aj) - inter);                         \
        if ((j0 + (JQ)) > i && iou > 0.6f) bits |= 1ull << (JQ);         \
    }

// ONE block per class, 1024 threads — R16 best-verified config (100.44us).
// Fully LDS-fused NMS: prefix-sum bucket (no atomics in load loop),
// rank-by-count sort (4x ds_read_b128 in flight), upper-triangle wave-task
// mask build (8 independent broadcast reads), batch-8 speculative greedy
// scan + all-wave parallel fold. MSTRIDE=514 breaks the fold's 32-way bank
// conflict. R18's 640-block split-build regressed (memory-amplified amid
// poison-writeback) -- fused LDS masks avoid all global mask traffic.
__global__ __launch_bounds__(1024, 4) void nms_fused_kernel(
    const uint64_t* __restrict__ g_key, const float4* __restrict__ g_boxin,
    float* __restrict__ out)
{
    int c = blockIdx.x;
    int tid = threadIdx.x;
    int wid  = tid >> 6;
    int lane = tid & 63;

    __shared__ alignas(16) uint64_t key_s[CAP];   // 4 KB (class-c keys)
    __shared__ float4   boxu_s[CAP];              // 8 KB (matching offset boxes)
    __shared__ float4   sbox_s[CAP + 64];         // 9 KB (sorted, +64 sentinel)
    __shared__ int      sg_s[CAP];                // 2 KB (sorted -> pred idx)
    __shared__ uint64_t mask_s[MW * MSTRIDE];     // 32.1 KB (stride-padded)
    __shared__ int      wsum[16];                 // per-wave match totals
    __shared__ uint64_t kw_s;                     // kept mask broadcast
    __shared__ uint64_t fold_s[MW];               // per-word fold results

    // ---- phase 0 pass 1: count matches (13 independent ulonglong2 loads)
    const ulonglong2* kp = (const ulonglong2*)g_key;
    const int HALF = NPRED / 2;              // 12600
    int cnt = 0;
#pragma unroll
    for (int j = 0; j < 13; j++) {
        int idx = j * 1024 + tid;
        if (idx < HALF) {
            ulonglong2 kv = kp[idx];
            cnt += ((int)(kv.x >> 47) == c) + ((int)(kv.y >> 47) == c);
        }
    }
    int pre = cnt;                           // wave-inclusive shfl prefix
#pragma unroll
    for (int d = 1; d < 64; d <<= 1) {
        int vv = __shfl_up(pre, d);
        if (lane >= d) pre += vv;
    }
    if (lane == 63) wsum[wid] = pre;
    __syncthreads();
    int wbase = 0, ntot = 0;
#pragma unroll
    for (int wq = 0; wq < 16; wq++) {
        int t16 = wsum[wq];
        if (wq < wid) wbase += t16;
        ntot += t16;
    }
    int base = wbase + pre - cnt;            // exclusive prefix for this thread

    // ---- phase 0 pass 2: re-read (L1-hot) and write at computed offsets
    {
        int wr = base;
#pragma unroll
        for (int j = 0; j < 13; j++) {
            int idx = j * 1024 + tid;
            if (idx < HALF) {
                ulonglong2 kv = kp[idx];
                if ((int)(kv.x >> 47) == c && wr < CAP) key_s[wr++] = kv.x;
                if ((int)(kv.y >> 47) == c && wr < CAP) key_s[wr++] = kv.y;
            }
        }
    }
    __syncthreads();
    int n = ntot; if (n > CAP) n = CAP;
    if (n == 0) return;                       // uniform
    int nw = (n + 63) >> 6;

    // ---- phase 0b: gather boxes by g; sentinel-fill pad
    for (int i = tid; i < n; i += 1024)
        boxu_s[i] = g_boxin[key_s[i] & 0x7FFF];
    for (int i = n + tid; i < n + 64; i += 1024)
        sbox_s[i] = make_float4(3e30f, 3e30f, 3e30f, 3e30f);
    __syncthreads();

    // ---- rank-by-count sort (keys unique: low 15 bits = global pred idx)
    for (int i0 = 0; i0 < n; i0 += 256) {
        int item = i0 + (tid >> 2);
        int sub  = tid & 3;
        bool act = item < n;
        int r = 0;
        uint64_t k = 0;
        if (act) {
            k = key_s[item];
            int nq = (((n + 3) >> 2) + 1) & ~1;    // even, >= ceil(n/4)
            int lo = sub * nq; if (lo > n) lo = n;
            int hi = lo + nq;  if (hi > n) hi = n;
            int jj = lo;
            for (; jj + 8 <= hi; jj += 8) {        // 4x ds_read_b128 in flight
                ulonglong2 p0 = *(const ulonglong2*)&key_s[jj];
                ulonglong2 p1 = *(const ulonglong2*)&key_s[jj + 2];
                ulonglong2 p2 = *(const ulonglong2*)&key_s[jj + 4];
                ulonglong2 p3 = *(const ulonglong2*)&key_s[jj + 6];
                r += (p0.x < k) + (p0.y < k) + (p1.x < k) + (p1.y < k)
                   + (p2.x < k) + (p2.y < k) + (p3.x < k) + (p3.y < k);
            }
            for (; jj + 2 <= hi; jj += 2) {
                ulonglong2 p0 = *(const ulonglong2*)&key_s[jj];
                r += (p0.x < k) + (p0.y < k);
            }
            if (jj < hi) r += (key_s[jj] < k);
        }
        r += __shfl_xor(r, 1);                // quad reduce (4 lanes/item)
        r += __shfl_xor(r, 2);
        if (act && sub == 0) {
            sbox_s[r] = boxu_s[item];
            sg_s[r]   = (int)(k & 0x7FFF);
        }
    }
    __syncthreads();

    // ---- mask build: upper-triangle words, wave-task tiles; 8 independent
    // broadcast loads in flight per chunk
    {
        int T = nw * (nw + 1) / 2;
        for (int t = wid; t < T; t += 16) {
            int w = 0, acc = 0;               // triangular decode (wave-uniform)
            while (t >= acc + w + 1) { acc += w + 1; w++; }
            int ib = t - acc;                 // 0..w
            int i  = (ib << 6) + lane;        // <= n+62 (covered by pad)
            float4 b4 = sbox_s[i];
            float Ai = (b4.z - b4.x) * (b4.w - b4.y);
            int j0 = w << 6;
            uint64_t bits = 0;
#pragma unroll
            for (int jq0 = 0; jq0 < 64; jq0 += 8) {
                float4 q0 = sbox_s[j0 + jq0 + 0];
                float4 q1 = sbox_s[j0 + jq0 + 1];
                float4 q2 = sbox_s[j0 + jq0 + 2];
                float4 q3 = sbox_s[j0 + jq0 + 3];
                float4 q4 = sbox_s[j0 + jq0 + 4];
                float4 q5 = sbox_s[j0 + jq0 + 5];
                float4 q6 = sbox_s[j0 + jq0 + 6];
                float4 q7 = sbox_s[j0 + jq0 + 7];
                IOUBIT(q0, jq0 + 0); IOUBIT(q1, jq0 + 1);
                IOUBIT(q2, jq0 + 2); IOUBIT(q3, jq0 + 3);
                IOUBIT(q4, jq0 + 4); IOUBIT(q5, jq0 + 5);
                IOUBIT(q6, jq0 + 6); IOUBIT(q7, jq0 + 7);
            }
            if (i < n) mask_s[w * MSTRIDE + i] = bits;
        }
    }
    __syncthreads();

    // ---- greedy bitmask scan: wave-0 serial core (BATCH-8 speculative
    // chain) + all-wave parallel fold. Kept-set == ref's greedy NMS.
    uint64_t removed = 0;                      // wave 0: lane L<8 holds word L
    for (int w = 0; w < nw; w++) {
        if (wid == 0) {
            uint64_t rw = __shfl(removed, w);
            int row = (w << 6) + lane;
            uint64_t diag = (row < n) ? mask_s[w * MSTRIDE + row] : 0ull;
            int rem = n - (w << 6);
            uint64_t valid = (rem >= 64) ? ~0ull : ((1ull << rem) - 1ull);
            uint64_t nulls = __ballot(diag == 0ull);
            uint64_t cand = ~rw & valid;
            uint64_t kw = 0;
            uint64_t it = cand & ~nulls;       // rows with in-word forward bits
            while (it) {
                uint64_t tmp = it;
                int b0 = __ffsll((unsigned long long)tmp) - 1; tmp &= tmp - 1;
                int b1 = tmp ? __ffsll((unsigned long long)tmp) - 1 : -1; tmp &= tmp - 1;
                int b2 = tmp ? __ffsll((unsigned long long)tmp) - 1 : -1; tmp &= tmp - 1;
                int b3 = tmp ? __ffsll((unsigned long long)tmp) - 1 : -1; tmp &= tmp - 1;
                int b4i = tmp ? __ffsll((unsigned long long)tmp) - 1 : -1; tmp &= tmp - 1;
                int b5 = tmp ? __ffsll((unsigned long long)tmp) - 1 : -1; tmp &= tmp - 1;
                int b6 = tmp ? __ffsll((unsigned long long)tmp) - 1 : -1; tmp &= tmp - 1;
                int b7 = tmp ? __ffsll((unsigned long long)tmp) - 1 : -1;
                // 8 INDEPENDENT diag fetches (latency overlaps)
                uint64_t d0 = __shfl(diag, b0);
                uint64_t d1 = __shfl(diag, b1 < 0 ? 0 : b1);
                uint64_t d2 = __shfl(diag, b2 < 0 ? 0 : b2);
                uint64_t d3 = __shfl(diag, b3 < 0 ? 0 : b3);
                uint64_t d4 = __shfl(diag, b4i < 0 ? 0 : b4i);
                uint64_t d5 = __shfl(diag, b5 < 0 ? 0 : b5);
                uint64_t d6 = __shfl(diag, b6 < 0 ? 0 : b6);
                uint64_t d7 = __shfl(diag, b7 < 0 ? 0 : b7);
                // serial register resolve (exact greedy recurrence)
                uint64_t rm = 0, proc = 1ull << b0;
                kw |= 1ull << b0; rm |= d0;    // lowest bit always kept
                if (b1 >= 0) { proc |= 1ull << b1; if (!((rm >> b1) & 1)) { kw |= 1ull << b1; rm |= d1; } }
                if (b2 >= 0) { proc |= 1ull << b2; if (!((rm >> b2) & 1)) { kw |= 1ull << b2; rm |= d2; } }
                if (b3 >= 0) { proc |= 1ull << b3; if (!((rm >> b3) & 1)) { kw |= 1ull << b3; rm |= d3; } }
                if (b4i >= 0) { proc |= 1ull << b4i; if (!((rm >> b4i) & 1)) { kw |= 1ull << b4i; rm |= d4; } }
                if (b5 >= 0) { proc |= 1ull << b5; if (!((rm >> b5) & 1)) { kw |= 1ull << b5; rm |= d5; } }
                if (b6 >= 0) { proc |= 1ull << b6; if (!((rm >> b6) & 1)) { kw |= 1ull << b6; rm |= d6; } }
                if (b7 >= 0) { proc |= 1ull << b7; if (!((rm >> b7) & 1)) { kw |= 1ull << b7; rm |= d7; } }
                it &= ~rm; cand &= ~rm;
                it &= ~proc;
            }
            kw |= cand & nulls;                // surviving zero-diag rows kept
            if (lane == 0) kw_s = kw;
            if (row < n && ((kw >> lane) & 1))
                out[(size_t)sg_s[row] * 7 + 6] = 1.0f;
        }
        __syncthreads();                       // kw_s visible to all waves
        if (wid >= w && wid < nw) {
            uint64_t kwv = kw_s;
            uint64_t fw = 0;
            if ((kwv >> lane) & 1)
                fw = mask_s[wid * MSTRIDE + (w << 6) + lane];
            fw |= __shfl_xor(fw, 1);
            fw |= __shfl_xor(fw, 2);
            fw |= __shfl_xor(fw, 4);
            fw |= __shfl_xor(fw, 8);
            fw |= __shfl_xor(fw, 16);
            fw |= __shfl_xor(fw, 32);
            if (lane == 0) fold_s[wid] = fw;
        }
        __syncthreads();                       // fold_s visible to wave 0
        if (wid == 0 && lane >= w && lane < nw)
            removed |= fold_s[lane];
    }
}

extern "C" void kernel_launch(void* const* d_in, const int* in_sizes, int n_in,
                              void* d_out, int out_size, void* d_ws, size_t ws_size,
                              hipStream_t stream) {
    const float* ps = (const float*)d_in[0];
    const float* pm = (const float*)d_in[1];
    const float* pl = (const float*)d_in[2];
    float* out = (float*)d_out;

    char* ws = (char*)d_ws;
    float4*   g_boxin = (float4*)ws;                       // 403,200 B (dense by g)
    uint64_t* g_key   = (uint64_t*)(ws + 409600);          // 201,600 B (dense by g)

    decode_kernel<<<dim3(NCHUNK, 3), 64, 0, stream>>>(ps, pm, pl, out, g_boxin, g_key);
    nms_fused_kernel<<<NCLS, 1024, 0, stream>>>(g_key, g_boxin, out);
}